// Round 1
// baseline (243.049 us; speedup 1.0000x reference)
//
#include <hip/hip_runtime.h>

// Go board features: group labels, liberties, legality, scores, group-pooled features.
// B=2048 boards, 19x19, D=64. One block per board, 1024 threads, ~97KB LDS.

constexpr int BOARD = 19;
constexpr int NN = BOARD * BOARD;   // 361
constexpr int DD = 64;
constexpr int NQ = NN * (DD / 4);   // 5776 float4 per board

__global__ __launch_bounds__(1024) void go_fused(
    const int* __restrict__ stones,      // B*2*361, dtype detected at runtime
    const int* __restrict__ ko,          // B*2 int32
    const float* __restrict__ feat,      // B*361*64 f32
    float* __restrict__ out_feats,       // B*361*64 f32
    float* __restrict__ o_libs,          // B*361 (float-encoded int)
    float* __restrict__ o_legal,         // B*361 (0.0/1.0)
    float* __restrict__ o_scores)        // B*2  (float-encoded int)
{
    const int b = blockIdx.x;
    const int tid = threadIdx.x;

    __shared__ float s_pool[NN * DD];    // 92416 B
    __shared__ int s_color[NN];          // 0 black, 1 white, -1 empty
    __shared__ int s_label[NN];
    __shared__ int s_libs[NN];
    __shared__ int s_cnt[2];
    __shared__ int s_changed;
    __shared__ unsigned int s_orw;

    // ---- detect stones storage dtype (bool-as-u8 vs int32 vs f32) ----
    // OR-reduce first 2048 words (8KB, safe under the smallest interpretation:
    // the bool buffer is >=1.4MB). Same result in every block -> uniform mode.
    if (tid == 0) { s_orw = 0u; s_cnt[0] = 0; s_cnt[1] = 0; }
    __syncthreads();
    {
        unsigned int acc = 0u;
        const unsigned int* w = (const unsigned int*)stones;
        for (int i = tid; i < 2048; i += 1024) acc |= w[i];
        for (int off = 32; off > 0; off >>= 1)
            acc |= (unsigned int)__shfl_xor((int)acc, off, 64);
        if ((tid & 63) == 0 && acc) atomicOr(&s_orw, acc);
    }
    // zero pooling buffer meanwhile
    {
        float4 z = make_float4(0.f, 0.f, 0.f, 0.f);
        float4* p4 = (float4*)s_pool;
        for (int p = tid; p < NQ; p += 1024) p4[p] = z;
    }
    __syncthreads();
    const unsigned int orw = s_orw;
    // int32 0/1 -> OR <= 1 ; packed bool bytes -> bytes each 0/1 ;
    // float 0.0/1.0 -> OR == 0x3F800000
    const int mode = (orw <= 1u) ? 0 : (((orw & 0xFEFEFEFEu) == 0u) ? 1 : 2);

    // ---- init color / labels ----
    if (tid < NN) {
        int blk, wht;
        const size_t base = (size_t)b * (2 * NN);
        if (mode == 0) {
            blk = stones[base + tid] != 0;
            wht = stones[base + NN + tid] != 0;
        } else if (mode == 1) {
            const unsigned char* s8 = (const unsigned char*)stones;
            blk = s8[base + tid] != 0;
            wht = s8[base + NN + tid] != 0;
        } else {
            const float* sf = (const float*)stones;
            blk = sf[base + tid] != 0.0f;
            wht = sf[base + NN + tid] != 0.0f;
        }
        if (blk) wht = 0;                 // white = stones1 & ~stones0
        s_color[tid] = blk ? 0 : (wht ? 1 : -1);
        s_label[tid] = tid;
        s_libs[tid] = 0;
    }

    // ---- label propagation: min over same-color 4-neighbors + pointer jump ----
    // Monotone (labels only decrease, always stay inside the component), so the
    // in-place races are benign. Changed-flag loop; cap as a hang guard.
    for (int it = 0; it < 512; ++it) {
        __syncthreads();                  // also covers init writes on first pass
        if (tid == 0) s_changed = 0;
        __syncthreads();
        if (tid < NN) {
            const int c = s_color[tid];
            if (c >= 0) {
                int m = s_label[tid];
                const int r = tid / BOARD;
                const int q = tid - r * BOARD;
                if (r > 0         && s_color[tid - BOARD] == c) m = min(m, s_label[tid - BOARD]);
                if (r < BOARD - 1 && s_color[tid + BOARD] == c) m = min(m, s_label[tid + BOARD]);
                if (q > 0         && s_color[tid - 1] == c)     m = min(m, s_label[tid - 1]);
                if (q < BOARD - 1 && s_color[tid + 1] == c)     m = min(m, s_label[tid + 1]);
                m = min(m, s_label[m]);   // one pointer-jump step
                if (m < s_label[tid]) { s_label[tid] = m; s_changed = 1; }
            }
        }
        __syncthreads();
        if (!s_changed) break;
    }

    // ---- liberties (dedup in DIRS order: up,down,left,right) + stone counts ----
    if (tid < NN) {
        const int c = s_color[tid];
        if (c < 0) {
            const int r = tid / BOARD;
            const int q = tid - r * BOARD;
            const int l0 = (r > 0         && s_color[tid - BOARD] >= 0) ? s_label[tid - BOARD] : NN;
            const int l1 = (r < BOARD - 1 && s_color[tid + BOARD] >= 0) ? s_label[tid + BOARD] : NN;
            const int l2 = (q > 0         && s_color[tid - 1] >= 0)     ? s_label[tid - 1]     : NN;
            const int l3 = (q < BOARD - 1 && s_color[tid + 1] >= 0)     ? s_label[tid + 1]     : NN;
            if (l0 < NN)                                     atomicAdd(&s_libs[l0], 1);
            if (l1 < NN && l1 != l0)                         atomicAdd(&s_libs[l1], 1);
            if (l2 < NN && l2 != l0 && l2 != l1)             atomicAdd(&s_libs[l2], 1);
            if (l3 < NN && l3 != l0 && l3 != l1 && l3 != l2) atomicAdd(&s_libs[l3], 1);
        } else {
            atomicAdd(&s_cnt[c], 1);
        }
    }

    // ---- feature pooling: scatter-add stone features into group root slots ----
    // lane layout: p = cell*16 + quad -> wave covers 4 cells x 16 float4s, LDS
    // addresses are 64 consecutive floats per label -> conflict-free (2-way).
    const float4* f4 = (const float4*)(feat + (size_t)b * NN * DD);
    for (int p = tid; p < NQ; p += 1024) {
        const int cell = p >> 4;
        if (s_color[cell] >= 0) {
            const float4 v = f4[p];
            const int base = s_label[cell] * DD + ((p & 15) << 2);
            atomicAdd(&s_pool[base + 0], v.x);
            atomicAdd(&s_pool[base + 1], v.y);
            atomicAdd(&s_pool[base + 2], v.z);
            atomicAdd(&s_pool[base + 3], v.w);
        }
    }
    __syncthreads();   // covers s_pool scatter, s_libs, s_cnt

    // ---- writes (everything as f32; tuple is read back with one dtype) ----
    float4* o4 = (float4*)(out_feats + (size_t)b * NN * DD);
    const float4* p4 = (const float4*)s_pool;
    for (int p = tid; p < NQ; p += 1024) {
        const int cell = p >> 4;
        float4 v = make_float4(0.f, 0.f, 0.f, 0.f);
        if (s_color[cell] >= 0) v = p4[s_label[cell] * (DD / 4) + (p & 15)];
        o4[p] = v;
    }
    if (tid < NN) {
        o_libs[(size_t)b * NN + tid] = (float)s_libs[tid];
        bool legal = (s_color[tid] < 0);
        const int kr = ko[2 * b];
        const int kc = ko[2 * b + 1];
        if (kr >= 0) {
            const int krr = min(max(kr, 0), BOARD - 1);
            const int kcc = min(max(kc, 0), BOARD - 1);
            if (tid == krr * BOARD + kcc) legal = false;
        }
        o_legal[(size_t)b * NN + tid] = legal ? 1.0f : 0.0f;
    }
    if (tid == 0) {
        o_scores[(size_t)b * 2 + 0] = (float)s_cnt[0];
        o_scores[(size_t)b * 2 + 1] = (float)s_cnt[1];
    }
}

extern "C" void kernel_launch(void* const* d_in, const int* in_sizes, int n_in,
                              void* d_out, int out_size, void* d_ws, size_t ws_size,
                              hipStream_t stream) {
    // setup_inputs order: stones, ko_points, current_player, features
    const int* stones = (const int*)d_in[0];
    const int* ko     = (const int*)d_in[1];
    const float* feat = (const float*)d_in[3];
    float* out        = (float*)d_out;

    const int B = in_sizes[2];   // current_player has B elements

    float* o_feats  = out;
    float* o_libs   = o_feats + (size_t)B * NN * DD;
    float* o_legal  = o_libs  + (size_t)B * NN;
    float* o_scores = o_legal + (size_t)B * NN;

    go_fused<<<B, 1024, 0, stream>>>(stones, ko, feat,
                                     o_feats, o_libs, o_legal, o_scores);
}

// Round 2
// 214.531 us; speedup vs baseline: 1.1329x; 1.1329x over previous
//
#include <hip/hip_runtime.h>

// Go board features, split into 3 kernels by occupancy regime:
//  1) go_label: labels/libs/scores (small LDS, high occupancy); labels staged in o_legal
//  2) go_pool:  group-sum feature pooling, 32 channels per block (47KB LDS, 3 blocks/CU)
//  3) go_legal: final legality from staged labels + ko

constexpr int BOARD = 19;
constexpr int NN = BOARD * BOARD;   // 361
constexpr int DD = 64;
constexpr int CH = 32;              // channels per pooling block
constexpr int PSTR = CH + 1;        // padded pool stride (breaks bank aliasing)

// ---------------------------------------------------------------- kernel 1
__global__ __launch_bounds__(384) void go_label(
    const int* __restrict__ stones,   // B*2*361, storage dtype detected at runtime
    float* __restrict__ o_libs,       // B*361
    float* __restrict__ o_legal_tmp,  // B*361  <- staged: stone ? label : -1
    float* __restrict__ o_scores)     // B*2
{
    const int b = blockIdx.x;
    const int tid = threadIdx.x;

    __shared__ int s_color[NN];
    __shared__ int s_label[NN];
    __shared__ int s_libs[NN];
    __shared__ int s_cnt[2];
    __shared__ int s_changed;
    __shared__ unsigned int s_orw;

    if (tid == 0) { s_orw = 0u; s_cnt[0] = 0; s_cnt[1] = 0; }
    __syncthreads();

    // detect stones storage width (int32 0/1 vs packed bytes vs f32)
    {
        unsigned int acc = 0u;
        const unsigned int* w = (const unsigned int*)stones;
        for (int i = tid; i < 2048; i += 384) acc |= w[i];
        for (int off = 32; off > 0; off >>= 1)
            acc |= (unsigned int)__shfl_xor((int)acc, off, 64);
        if ((tid & 63) == 0 && acc) atomicOr(&s_orw, acc);
    }
    __syncthreads();
    const unsigned int orw = s_orw;
    const int mode = (orw <= 1u) ? 0 : (((orw & 0xFEFEFEFEu) == 0u) ? 1 : 2);

    if (tid < NN) {
        int blk, wht;
        const size_t base = (size_t)b * (2 * NN);
        if (mode == 0) {
            blk = stones[base + tid] != 0;
            wht = stones[base + NN + tid] != 0;
        } else if (mode == 1) {
            const unsigned char* s8 = (const unsigned char*)stones;
            blk = s8[base + tid] != 0;
            wht = s8[base + NN + tid] != 0;
        } else {
            const float* sf = (const float*)stones;
            blk = sf[base + tid] != 0.0f;
            wht = sf[base + NN + tid] != 0.0f;
        }
        if (blk) wht = 0;
        s_color[tid] = blk ? 0 : (wht ? 1 : -1);
        s_label[tid] = tid;
        s_libs[tid] = 0;
    }

    // min-label propagation over same-color 4-neighbors + one pointer-jump/iter
    for (int it = 0; it < 512; ++it) {
        __syncthreads();
        if (tid == 0) s_changed = 0;
        __syncthreads();
        if (tid < NN) {
            const int c = s_color[tid];
            if (c >= 0) {
                int m = s_label[tid];
                const int r = tid / BOARD;
                const int q = tid - r * BOARD;
                if (r > 0         && s_color[tid - BOARD] == c) m = min(m, s_label[tid - BOARD]);
                if (r < BOARD - 1 && s_color[tid + BOARD] == c) m = min(m, s_label[tid + BOARD]);
                if (q > 0         && s_color[tid - 1] == c)     m = min(m, s_label[tid - 1]);
                if (q < BOARD - 1 && s_color[tid + 1] == c)     m = min(m, s_label[tid + 1]);
                m = min(m, s_label[m]);
                if (m < s_label[tid]) { s_label[tid] = m; s_changed = 1; }
            }
        }
        __syncthreads();
        if (!s_changed) break;
    }

    // liberties (dedup in DIRS order) + stone counts
    if (tid < NN) {
        const int c = s_color[tid];
        if (c < 0) {
            const int r = tid / BOARD;
            const int q = tid - r * BOARD;
            const int l0 = (r > 0         && s_color[tid - BOARD] >= 0) ? s_label[tid - BOARD] : NN;
            const int l1 = (r < BOARD - 1 && s_color[tid + BOARD] >= 0) ? s_label[tid + BOARD] : NN;
            const int l2 = (q > 0         && s_color[tid - 1] >= 0)     ? s_label[tid - 1]     : NN;
            const int l3 = (q < BOARD - 1 && s_color[tid + 1] >= 0)     ? s_label[tid + 1]     : NN;
            if (l0 < NN)                                     atomicAdd(&s_libs[l0], 1);
            if (l1 < NN && l1 != l0)                         atomicAdd(&s_libs[l1], 1);
            if (l2 < NN && l2 != l0 && l2 != l1)             atomicAdd(&s_libs[l2], 1);
            if (l3 < NN && l3 != l0 && l3 != l1 && l3 != l2) atomicAdd(&s_libs[l3], 1);
        } else {
            atomicAdd(&s_cnt[c], 1);
        }
    }
    __syncthreads();

    if (tid < NN) {
        o_libs[(size_t)b * NN + tid] = (float)s_libs[tid];
        o_legal_tmp[(size_t)b * NN + tid] =
            (s_color[tid] >= 0) ? (float)s_label[tid] : -1.0f;
    }
    if (tid == 0) {
        o_scores[(size_t)b * 2 + 0] = (float)s_cnt[0];
        o_scores[(size_t)b * 2 + 1] = (float)s_cnt[1];
    }
}

// ---------------------------------------------------------------- kernel 2
__global__ __launch_bounds__(512) void go_pool(
    const float* __restrict__ feat,        // B*361*64
    const float* __restrict__ labels_tmp,  // staged labels in o_legal
    float* __restrict__ out_feats)         // B*361*64
{
    const int b = blockIdx.x >> 1;
    const int half = blockIdx.x & 1;
    const int tid = threadIdx.x;

    __shared__ float s_pool[NN * PSTR];    // 47652 B
    __shared__ int s_lab[NN];

    if (tid < NN)
        s_lab[tid] = (int)labels_tmp[(size_t)b * NN + tid];  // -1 for empty
    for (int i = tid; i < NN * PSTR; i += 512) s_pool[i] = 0.0f;
    __syncthreads();

    const float* fb = feat + (size_t)b * NN * DD + half * CH;
    constexpr int NP = NN * (CH / 4);      // 2888 float4 per half-board

    for (int p = tid; p < NP; p += 512) {
        const int cell = p >> 3;
        const int q = p & 7;
        const int lab = s_lab[cell];
        if (lab >= 0) {
            const float4 v = ((const float4*)(fb + cell * DD))[q];
            const int pb = lab * PSTR + (q << 2);
            atomicAdd(&s_pool[pb + 0], v.x);
            atomicAdd(&s_pool[pb + 1], v.y);
            atomicAdd(&s_pool[pb + 2], v.z);
            atomicAdd(&s_pool[pb + 3], v.w);
        }
    }
    __syncthreads();

    float* ob = out_feats + (size_t)b * NN * DD + half * CH;
    for (int p = tid; p < NP; p += 512) {
        const int cell = p >> 3;
        const int q = p & 7;
        const int lab = s_lab[cell];
        float4 v = make_float4(0.f, 0.f, 0.f, 0.f);
        if (lab >= 0) {
            const int pb = lab * PSTR + (q << 2);
            v = make_float4(s_pool[pb], s_pool[pb + 1], s_pool[pb + 2], s_pool[pb + 3]);
        }
        ((float4*)(ob + cell * DD))[q] = v;
    }
}

// ---------------------------------------------------------------- kernel 3
__global__ __launch_bounds__(384) void go_legal(
    const int* __restrict__ ko,     // B*2
    float* __restrict__ o_legal)    // in: staged labels; out: 0/1 legality
{
    const int b = blockIdx.x;
    const int tid = threadIdx.x;
    if (tid >= NN) return;

    const float t = o_legal[(size_t)b * NN + tid];
    bool legal = (t < 0.0f);        // empty
    const int kr = ko[2 * b];
    const int kc = ko[2 * b + 1];
    if (kr >= 0) {
        const int krr = min(max(kr, 0), BOARD - 1);
        const int kcc = min(max(kc, 0), BOARD - 1);
        if (tid == krr * BOARD + kcc) legal = false;
    }
    o_legal[(size_t)b * NN + tid] = legal ? 1.0f : 0.0f;
}

// ---------------------------------------------------------------- launch
extern "C" void kernel_launch(void* const* d_in, const int* in_sizes, int n_in,
                              void* d_out, int out_size, void* d_ws, size_t ws_size,
                              hipStream_t stream) {
    // setup_inputs order: stones, ko_points, current_player, features
    const int* stones = (const int*)d_in[0];
    const int* ko     = (const int*)d_in[1];
    const float* feat = (const float*)d_in[3];
    float* out        = (float*)d_out;

    const int B = in_sizes[2];   // current_player has B elements

    float* o_feats  = out;
    float* o_libs   = o_feats + (size_t)B * NN * DD;
    float* o_legal  = o_libs  + (size_t)B * NN;
    float* o_scores = o_legal + (size_t)B * NN;

    go_label<<<B, 384, 0, stream>>>(stones, o_libs, o_legal, o_scores);
    go_pool <<<2 * B, 512, 0, stream>>>(feat, o_legal, o_feats);
    go_legal<<<B, 384, 0, stream>>>(ko, o_legal);
}

// Round 3
// 191.532 us; speedup vs baseline: 1.2690x; 1.1201x over previous
//
#include <hip/hip_runtime.h>

// Go board features, fully fused: one block per board (384 threads, ~10KB LDS).
// Labels via min-propagation; pooling via per-label member lists (gather-sum,
// no FP atomics, no big LDS pool buffer) -> 5 blocks/CU resident.

constexpr int BOARD = 19;
constexpr int NN = BOARD * BOARD;   // 361
constexpr int DD = 64;
constexpr int NT = 384;             // 6 waves
constexpr int NQ = NN * (DD / 4);   // 5776 float4 per board

__global__ __launch_bounds__(NT) void go_board(
    const int* __restrict__ stones,   // B*2*361, storage dtype detected at runtime
    const int* __restrict__ ko,       // B*2 int32
    const float* __restrict__ feat,   // B*361*64 f32
    float* __restrict__ o_feats,      // B*361*64
    float* __restrict__ o_libs,       // B*361
    float* __restrict__ o_legal,      // B*361
    float* __restrict__ o_scores)     // B*2
{
    const int b = blockIdx.x;
    const int tid = threadIdx.x;

    __shared__ int s_color[NN];       // 0 black, 1 white, -1 empty
    __shared__ int s_label[NN];
    __shared__ int s_libs[NN];
    __shared__ int s_cnt[NN];         // stones per root label
    __shared__ int s_start[NN];       // exclusive scan of s_cnt
    __shared__ int s_ptr[NN];         // fill cursor
    __shared__ int s_members[NN];     // cell indices grouped by label
    __shared__ int s_sc[2];
    __shared__ int s_changed;
    __shared__ unsigned int s_orw;

    if (tid == 0) { s_orw = 0u; s_sc[0] = 0; s_sc[1] = 0; }
    __syncthreads();

    // ---- detect stones storage width (int32 0/1 vs packed bytes vs f32) ----
    // 3KB read: safe under the smallest interpretation (bool bytes -> 1.4MB buf).
    {
        unsigned int acc = 0u;
        const unsigned int* w = (const unsigned int*)stones;
        for (int i = tid; i < 768; i += NT) acc |= w[i];
        for (int off = 32; off > 0; off >>= 1)
            acc |= (unsigned int)__shfl_xor((int)acc, off, 64);
        if ((tid & 63) == 0 && acc) atomicOr(&s_orw, acc);
    }
    __syncthreads();
    const unsigned int orw = s_orw;
    const int mode = (orw <= 1u) ? 0 : (((orw & 0xFEFEFEFEu) == 0u) ? 1 : 2);

    // ---- init color / labels / counters ----
    if (tid < NN) {
        int blk, wht;
        const size_t base = (size_t)b * (2 * NN);
        if (mode == 0) {
            blk = stones[base + tid] != 0;
            wht = stones[base + NN + tid] != 0;
        } else if (mode == 1) {
            const unsigned char* s8 = (const unsigned char*)stones;
            blk = s8[base + tid] != 0;
            wht = s8[base + NN + tid] != 0;
        } else {
            const float* sf = (const float*)stones;
            blk = sf[base + tid] != 0.0f;
            wht = sf[base + NN + tid] != 0.0f;
        }
        if (blk) wht = 0;                 // white = stones1 & ~stones0
        s_color[tid] = blk ? 0 : (wht ? 1 : -1);
        s_label[tid] = tid;
        s_libs[tid] = 0;
        s_cnt[tid] = 0;
    }

    // ---- min-label propagation (same-color 4-neighbors) + pointer jump ----
    for (int it = 0; it < 64; ++it) {
        __syncthreads();                  // covers init on first pass
        if (tid == 0) s_changed = 0;
        __syncthreads();
        if (tid < NN) {
            const int c = s_color[tid];
            if (c >= 0) {
                int m = s_label[tid];
                const int r = tid / BOARD;
                const int q = tid - r * BOARD;
                if (r > 0         && s_color[tid - BOARD] == c) m = min(m, s_label[tid - BOARD]);
                if (r < BOARD - 1 && s_color[tid + BOARD] == c) m = min(m, s_label[tid + BOARD]);
                if (q > 0         && s_color[tid - 1] == c)     m = min(m, s_label[tid - 1]);
                if (q < BOARD - 1 && s_color[tid + 1] == c)     m = min(m, s_label[tid + 1]);
                m = min(m, s_label[m]);   // one pointer-jump step
                if (m < s_label[tid]) { s_label[tid] = m; s_changed = 1; }
            }
        }
        __syncthreads();
        if (!s_changed) break;
    }

    // ---- liberties (dedup in DIRS order), stone counts, group sizes ----
    if (tid < NN) {
        const int c = s_color[tid];
        if (c < 0) {
            const int r = tid / BOARD;
            const int q = tid - r * BOARD;
            const int l0 = (r > 0         && s_color[tid - BOARD] >= 0) ? s_label[tid - BOARD] : NN;
            const int l1 = (r < BOARD - 1 && s_color[tid + BOARD] >= 0) ? s_label[tid + BOARD] : NN;
            const int l2 = (q > 0         && s_color[tid - 1] >= 0)     ? s_label[tid - 1]     : NN;
            const int l3 = (q < BOARD - 1 && s_color[tid + 1] >= 0)     ? s_label[tid + 1]     : NN;
            if (l0 < NN)                                     atomicAdd(&s_libs[l0], 1);
            if (l1 < NN && l1 != l0)                         atomicAdd(&s_libs[l1], 1);
            if (l2 < NN && l2 != l0 && l2 != l1)             atomicAdd(&s_libs[l2], 1);
            if (l3 < NN && l3 != l0 && l3 != l1 && l3 != l2) atomicAdd(&s_libs[l3], 1);
        } else {
            atomicAdd(&s_sc[c], 1);
            atomicAdd(&s_cnt[s_label[tid]], 1);
        }
    }
    __syncthreads();

    // ---- exclusive scan of s_cnt (wave 0 only; 6 chunks of 64) ----
    if (tid < 64) {
        int carry = 0;
        for (int c = 0; c < 6; ++c) {
            const int i = c * 64 + tid;
            const int v = (i < NN) ? s_cnt[i] : 0;
            int x = v;
            for (int off = 1; off < 64; off <<= 1) {
                const int y = __shfl_up(x, off, 64);
                if (tid >= off) x += y;
            }
            if (i < NN) { s_start[i] = carry + x - v; s_ptr[i] = carry + x - v; }
            carry += __shfl(x, 63, 64);
        }
    }
    __syncthreads();

    // ---- fill member lists + small outputs ----
    if (tid < NN) {
        if (s_color[tid] >= 0) {
            const int pos = atomicAdd(&s_ptr[s_label[tid]], 1);
            s_members[pos] = tid;
        }
        o_libs[(size_t)b * NN + tid] = (float)s_libs[tid];
        bool legal = (s_color[tid] < 0);
        const int kr = ko[2 * b];
        const int kc = ko[2 * b + 1];
        if (kr >= 0) {
            const int krr = min(max(kr, 0), BOARD - 1);
            const int kcc = min(max(kc, 0), BOARD - 1);
            if (tid == krr * BOARD + kcc) legal = false;
        }
        o_legal[(size_t)b * NN + tid] = legal ? 1.0f : 0.0f;
    }
    if (tid == 0) {
        o_scores[(size_t)b * 2 + 0] = (float)s_sc[0];
        o_scores[(size_t)b * 2 + 1] = (float)s_sc[1];
    }
    __syncthreads();

    // ---- pooling: out[cell] = sum over group members (gather, no atomics) ----
    // lane = (cell, quad), quad fastest: each member-load instruction covers
    // 4 contiguous 256B feature rows -> fully coalesced; repeats hit L1/L2.
    const float4* f4 = (const float4*)feat + (size_t)b * NQ;
    float4* o4 = (float4*)o_feats + (size_t)b * NQ;
    for (int p = tid; p < NQ; p += NT) {
        const int cell = p >> 4;
        const int q = p & 15;
        float4 acc = make_float4(0.f, 0.f, 0.f, 0.f);
        if (s_color[cell] >= 0) {
            const int L = s_label[cell];
            const int s = s_start[L];
            const int e = s + s_cnt[L];
            for (int k = s; k < e; ++k) {
                const float4 v = f4[s_members[k] * 16 + q];
                acc.x += v.x; acc.y += v.y; acc.z += v.z; acc.w += v.w;
            }
        }
        o4[p] = acc;
    }
}

extern "C" void kernel_launch(void* const* d_in, const int* in_sizes, int n_in,
                              void* d_out, int out_size, void* d_ws, size_t ws_size,
                              hipStream_t stream) {
    // setup_inputs order: stones, ko_points, current_player, features
    const int* stones = (const int*)d_in[0];
    const int* ko     = (const int*)d_in[1];
    const float* feat = (const float*)d_in[3];
    float* out        = (float*)d_out;

    const int B = in_sizes[2];   // current_player has B elements

    float* o_feats  = out;
    float* o_libs   = o_feats + (size_t)B * NN * DD;
    float* o_legal  = o_libs  + (size_t)B * NN;
    float* o_scores = o_legal + (size_t)B * NN;

    go_board<<<B, NT, 0, stream>>>(stones, ko, feat,
                                   o_feats, o_libs, o_legal, o_scores);
}

// Round 4
// 92.041 us; speedup vs baseline: 2.6406x; 2.0809x over previous
//
#include <hip/hip_runtime.h>

// Go board features, fully fused: one block per board (384 threads, ~12KB LDS).
// Labels via min-propagation; pooling via wave-per-group: each group's sum is
// computed ONCE (4 members x 16 quads per wave, shfl-reduce) and broadcast to
// all members. Minimum HBM traffic, high MLP, 5 blocks/CU.

constexpr int BOARD = 19;
constexpr int NN = BOARD * BOARD;   // 361
constexpr int DD = 64;
constexpr int NT = 384;             // 6 waves
constexpr int NQ = NN * (DD / 4);   // 5776 float4 per board

__global__ __launch_bounds__(NT) void go_board(
    const int* __restrict__ stones,   // B*2*361, storage dtype detected at runtime
    const int* __restrict__ ko,       // B*2 int32
    const float* __restrict__ feat,   // B*361*64 f32
    float* __restrict__ o_feats,      // B*361*64
    float* __restrict__ o_libs,       // B*361
    float* __restrict__ o_legal,      // B*361
    float* __restrict__ o_scores)     // B*2
{
    const int b = blockIdx.x;
    const int tid = threadIdx.x;

    __shared__ int s_color[NN];       // 0 black, 1 white, -1 empty
    __shared__ int s_label[NN];
    __shared__ int s_libs[NN];
    __shared__ int s_cnt[NN];         // stones per root label
    __shared__ int s_start[NN];       // exclusive scan of s_cnt
    __shared__ int s_ptr[NN];         // fill cursor
    __shared__ int s_members[NN];     // cell indices grouped by label
    __shared__ int s_glist[NN];       // compacted list of group roots
    __shared__ int s_ng;              // number of groups
    __shared__ int s_sc[2];
    __shared__ int s_changed;
    __shared__ unsigned int s_orw;

    if (tid == 0) { s_orw = 0u; s_sc[0] = 0; s_sc[1] = 0; s_ng = 0; }
    __syncthreads();

    // ---- detect stones storage width (int32 0/1 vs packed bytes vs f32) ----
    {
        unsigned int acc = 0u;
        const unsigned int* w = (const unsigned int*)stones;
        for (int i = tid; i < 768; i += NT) acc |= w[i];
        for (int off = 32; off > 0; off >>= 1)
            acc |= (unsigned int)__shfl_xor((int)acc, off, 64);
        if ((tid & 63) == 0 && acc) atomicOr(&s_orw, acc);
    }
    __syncthreads();
    const unsigned int orw = s_orw;
    const int mode = (orw <= 1u) ? 0 : (((orw & 0xFEFEFEFEu) == 0u) ? 1 : 2);

    // ---- init color / labels / counters ----
    if (tid < NN) {
        int blk, wht;
        const size_t base = (size_t)b * (2 * NN);
        if (mode == 0) {
            blk = stones[base + tid] != 0;
            wht = stones[base + NN + tid] != 0;
        } else if (mode == 1) {
            const unsigned char* s8 = (const unsigned char*)stones;
            blk = s8[base + tid] != 0;
            wht = s8[base + NN + tid] != 0;
        } else {
            const float* sf = (const float*)stones;
            blk = sf[base + tid] != 0.0f;
            wht = sf[base + NN + tid] != 0.0f;
        }
        if (blk) wht = 0;                 // white = stones1 & ~stones0
        s_color[tid] = blk ? 0 : (wht ? 1 : -1);
        s_label[tid] = tid;
        s_libs[tid] = 0;
        s_cnt[tid] = 0;
    }

    // ---- min-label propagation (same-color 4-neighbors) + pointer jump ----
    for (int it = 0; it < 64; ++it) {
        __syncthreads();                  // covers init on first pass
        if (tid == 0) s_changed = 0;
        __syncthreads();
        if (tid < NN) {
            const int c = s_color[tid];
            if (c >= 0) {
                int m = s_label[tid];
                const int r = tid / BOARD;
                const int q = tid - r * BOARD;
                if (r > 0         && s_color[tid - BOARD] == c) m = min(m, s_label[tid - BOARD]);
                if (r < BOARD - 1 && s_color[tid + BOARD] == c) m = min(m, s_label[tid + BOARD]);
                if (q > 0         && s_color[tid - 1] == c)     m = min(m, s_label[tid - 1]);
                if (q < BOARD - 1 && s_color[tid + 1] == c)     m = min(m, s_label[tid + 1]);
                m = min(m, s_label[m]);   // one pointer-jump step
                if (m < s_label[tid]) { s_label[tid] = m; s_changed = 1; }
            }
        }
        __syncthreads();
        if (!s_changed) break;
    }

    // ---- liberties (dedup in DIRS order), stone counts, group sizes ----
    if (tid < NN) {
        const int c = s_color[tid];
        if (c < 0) {
            const int r = tid / BOARD;
            const int q = tid - r * BOARD;
            const int l0 = (r > 0         && s_color[tid - BOARD] >= 0) ? s_label[tid - BOARD] : NN;
            const int l1 = (r < BOARD - 1 && s_color[tid + BOARD] >= 0) ? s_label[tid + BOARD] : NN;
            const int l2 = (q > 0         && s_color[tid - 1] >= 0)     ? s_label[tid - 1]     : NN;
            const int l3 = (q < BOARD - 1 && s_color[tid + 1] >= 0)     ? s_label[tid + 1]     : NN;
            if (l0 < NN)                                     atomicAdd(&s_libs[l0], 1);
            if (l1 < NN && l1 != l0)                         atomicAdd(&s_libs[l1], 1);
            if (l2 < NN && l2 != l0 && l2 != l1)             atomicAdd(&s_libs[l2], 1);
            if (l3 < NN && l3 != l0 && l3 != l1 && l3 != l2) atomicAdd(&s_libs[l3], 1);
        } else {
            atomicAdd(&s_sc[c], 1);
            atomicAdd(&s_cnt[s_label[tid]], 1);
            if (s_label[tid] == tid) {                 // group root -> compact list
                const int gi = atomicAdd(&s_ng, 1);
                s_glist[gi] = tid;
            }
        }
    }
    __syncthreads();

    // ---- exclusive scan of s_cnt (wave 0 only; 6 chunks of 64) ----
    if (tid < 64) {
        int carry = 0;
        for (int c = 0; c < 6; ++c) {
            const int i = c * 64 + tid;
            const int v = (i < NN) ? s_cnt[i] : 0;
            int x = v;
            for (int off = 1; off < 64; off <<= 1) {
                const int y = __shfl_up(x, off, 64);
                if (tid >= off) x += y;
            }
            if (i < NN) { s_start[i] = carry + x - v; s_ptr[i] = carry + x - v; }
            carry += __shfl(x, 63, 64);
        }
    }
    __syncthreads();

    // ---- fill member lists + small outputs ----
    if (tid < NN) {
        if (s_color[tid] >= 0) {
            const int pos = atomicAdd(&s_ptr[s_label[tid]], 1);
            s_members[pos] = tid;
        }
        o_libs[(size_t)b * NN + tid] = (float)s_libs[tid];
        bool legal = (s_color[tid] < 0);
        const int kr = ko[2 * b];
        const int kc = ko[2 * b + 1];
        if (kr >= 0) {
            const int krr = min(max(kr, 0), BOARD - 1);
            const int kcc = min(max(kc, 0), BOARD - 1);
            if (tid == krr * BOARD + kcc) legal = false;
        }
        o_legal[(size_t)b * NN + tid] = legal ? 1.0f : 0.0f;
    }
    if (tid == 0) {
        o_scores[(size_t)b * 2 + 0] = (float)s_sc[0];
        o_scores[(size_t)b * 2 + 1] = (float)s_sc[1];
    }
    __syncthreads();

    // ---- pooling: one wave per group; sum once, broadcast to members ----
    // lane = mi*16 + q: 4 member-lanes x 16 quads; loads/stores cover 4
    // contiguous 256B rows per instruction. shfl_xor(16,32) reduces over mi.
    const float4* f4 = (const float4*)feat + (size_t)b * NQ;
    float4* o4 = (float4*)o_feats + (size_t)b * NQ;
    const int wave = tid >> 6;
    const int lane = tid & 63;
    const int mi = lane >> 4;
    const int q  = lane & 15;
    const int ng = s_ng;
    for (int g = wave; g < ng; g += NT / 64) {
        const int root = s_glist[g];
        const int s = s_start[root];
        const int cnt = s_cnt[root];
        float4 acc = make_float4(0.f, 0.f, 0.f, 0.f);
        for (int k = mi; k < cnt; k += 4) {
            const float4 v = f4[s_members[s + k] * 16 + q];
            acc.x += v.x; acc.y += v.y; acc.z += v.z; acc.w += v.w;
        }
        // reduce across the 4 member-lanes (lane strides of 16 within the wave)
        acc.x += __shfl_xor(acc.x, 16); acc.y += __shfl_xor(acc.y, 16);
        acc.z += __shfl_xor(acc.z, 16); acc.w += __shfl_xor(acc.w, 16);
        acc.x += __shfl_xor(acc.x, 32); acc.y += __shfl_xor(acc.y, 32);
        acc.z += __shfl_xor(acc.z, 32); acc.w += __shfl_xor(acc.w, 32);
        // broadcast-write the group sum to every member row
        for (int k = mi; k < cnt; k += 4) {
            o4[s_members[s + k] * 16 + q] = acc;
        }
    }
    // zero-fill empty cells
    for (int p = tid; p < NQ; p += NT) {
        const int cell = p >> 4;
        if (s_color[cell] < 0)
            o4[p] = make_float4(0.f, 0.f, 0.f, 0.f);
    }
}

extern "C" void kernel_launch(void* const* d_in, const int* in_sizes, int n_in,
                              void* d_out, int out_size, void* d_ws, size_t ws_size,
                              hipStream_t stream) {
    // setup_inputs order: stones, ko_points, current_player, features
    const int* stones = (const int*)d_in[0];
    const int* ko     = (const int*)d_in[1];
    const float* feat = (const float*)d_in[3];
    float* out        = (float*)d_out;

    const int B = in_sizes[2];   // current_player has B elements

    float* o_feats  = out;
    float* o_libs   = o_feats + (size_t)B * NN * DD;
    float* o_legal  = o_libs  + (size_t)B * NN;
    float* o_scores = o_legal + (size_t)B * NN;

    go_board<<<B, NT, 0, stream>>>(stones, ko, feat,
                                   o_feats, o_libs, o_legal, o_scores);
}